// Round 1
// baseline (656.349 us; speedup 1.0000x reference)
//
#include <hip/hip_runtime.h>
#include <math.h>

#define T_DIM 2048
#define F_DIM 513
#define K_DIM 6
#define N_ITER 10

// ws float offsets
#define OFF_W    0            // 513*36*2 = 36936 floats (complex W[f][k][m])
#define OFF_WT   36936        // 6*2048 = 12288 floats
#define OFF_V    49224        // 513*6*36*2 = 221616 floats
#define OFF_DONE 270840       // int flag (stored in float slot)
#define OFF_PART 270844       // 33*2 = 66 floats

// ---------------------------------------------------------------- init W = I
__global__ void initW(float* __restrict__ ws) {
    int idx = blockIdx.x * 256 + threadIdx.x;
    if (idx < F_DIM * 36) {
        int e = idx % 36;
        int a = e / 6, b = e % 6;
        ws[OFF_W + idx * 2]     = (a == b) ? 1.0f : 0.0f;
        ws[OFF_W + idx * 2 + 1] = 0.0f;
    }
    if (idx == 0) {
        *(int*)(ws + OFF_DONE) = 0;
    }
}

// ------------------------------------------- transpose X (K,T,F) -> Xt (F,K,T)
__global__ __launch_bounds__(256) void transp(const float2* __restrict__ X,
                                              float2* __restrict__ Xt) {
    __shared__ float2 tile[32][33];
    int k  = blockIdx.z;
    int t0 = blockIdx.x * 32;
    int f0 = blockIdx.y * 32;
    int tx = threadIdx.x & 31, ty = threadIdx.x >> 5;  // tx 0..31, ty 0..7
#pragma unroll
    for (int j = 0; j < 4; ++j) {
        int t = t0 + ty + j * 8;
        int f = f0 + tx;
        if (f < F_DIM) tile[ty + j * 8][tx] = X[(k * T_DIM + t) * F_DIM + f];
    }
    __syncthreads();
#pragma unroll
    for (int j = 0; j < 4; ++j) {
        int f = f0 + ty + j * 8;
        int t = t0 + tx;
        if (f < F_DIM) Xt[(f * K_DIM + k) * T_DIM + t] = tile[tx][ty + j * 8];
    }
}

// ----------------------------- pass A: wt[k,t] = 1/clip(sqrt(clip(sum_f |Y|^2)))
__global__ __launch_bounds__(512) void passA(const float2* __restrict__ X,
                                             float* __restrict__ ws) {
    if (*(const int*)(ws + OFF_DONE)) return;
    const float2* W = (const float2*)(ws + OFF_W);
    float* wt = ws + OFF_WT;
    int t0  = blockIdx.x * 8;
    int tid = threadIdx.x;

    float s[48];
#pragma unroll
    for (int i = 0; i < 48; ++i) s[i] = 0.0f;

    for (int f = tid; f < F_DIM; f += 512) {
        float2 w[36];
#pragma unroll
        for (int i = 0; i < 36; ++i) w[i] = W[f * 36 + i];
#pragma unroll
        for (int tl = 0; tl < 8; ++tl) {
            int t = t0 + tl;
            float2 x[6];
#pragma unroll
            for (int m = 0; m < 6; ++m) x[m] = X[(m * T_DIM + t) * F_DIM + f];
#pragma unroll
            for (int k = 0; k < 6; ++k) {
                float yr = 0.0f, yi = 0.0f;
#pragma unroll
                for (int m = 0; m < 6; ++m) {
                    float2 wk = w[k * 6 + m];
                    yr += wk.x * x[m].x - wk.y * x[m].y;
                    yi += wk.x * x[m].y + wk.y * x[m].x;
                }
                s[k * 8 + tl] += yr * yr + yi * yi;
            }
        }
    }
    // reduce across 512 threads (f-lanes)
#pragma unroll
    for (int i = 0; i < 48; ++i) {
        float v = s[i];
#pragma unroll
        for (int d = 1; d < 64; d <<= 1) v += __shfl_xor(v, d);
        s[i] = v;
    }
    __shared__ float part[8][48];
    int wave = tid >> 6, lane = tid & 63;
    if (lane == 0) {
#pragma unroll
        for (int i = 0; i < 48; ++i) part[wave][i] = s[i];
    }
    __syncthreads();
    if (tid < 48) {
        float r2 = 0.0f;
#pragma unroll
        for (int w = 0; w < 8; ++w) r2 += part[w][tid];
        int k = tid >> 3, tl = tid & 7;
        float r = sqrtf(fmaxf(r2, 1e-10f));
        wt[k * T_DIM + t0 + tl] = 1.0f / fmaxf(r, 1e-10f);
    }
}

// ----------------------------- pass B: V[f,k,a,b] = (1/T) sum_t wt * x_a * conj(x_b)
__global__ __launch_bounds__(64) void passB(const float2* __restrict__ Xt,
                                            float* __restrict__ ws) {
    if (*(const int*)(ws + OFF_DONE)) return;
    const float* wt = ws + OFF_WT;
    float* V = ws + OFF_V;
    int f = blockIdx.x;
    int kg = blockIdx.y;          // k group: k = 3*kg + j
    int lane = threadIdx.x;       // 64 threads

    float accd[3][6];
    float accr[3][15];
    float acci[3][15];
#pragma unroll
    for (int j = 0; j < 3; ++j) {
#pragma unroll
        for (int a = 0; a < 6; ++a) accd[j][a] = 0.0f;
#pragma unroll
        for (int p = 0; p < 15; ++p) { accr[j][p] = 0.0f; acci[j][p] = 0.0f; }
    }

    const float2* xb = Xt + f * K_DIM * T_DIM;
    for (int t = lane; t < T_DIM; t += 64) {
        float w0 = wt[(3 * kg + 0) * T_DIM + t];
        float w1 = wt[(3 * kg + 1) * T_DIM + t];
        float w2 = wt[(3 * kg + 2) * T_DIM + t];
        float2 x[6];
#pragma unroll
        for (int m = 0; m < 6; ++m) x[m] = xb[m * T_DIM + t];
        float od[6], opr[15], opi[15];
#pragma unroll
        for (int a = 0; a < 6; ++a) od[a] = x[a].x * x[a].x + x[a].y * x[a].y;
#pragma unroll
        for (int a = 1; a < 6; ++a) {
#pragma unroll
            for (int b = 0; b < 6; ++b) {
                if (b < a) {
                    int p = a * (a - 1) / 2 + b;
                    opr[p] = x[a].x * x[b].x + x[a].y * x[b].y;
                    opi[p] = x[a].y * x[b].x - x[a].x * x[b].y;
                }
            }
        }
#pragma unroll
        for (int a = 0; a < 6; ++a) {
            accd[0][a] += w0 * od[a];
            accd[1][a] += w1 * od[a];
            accd[2][a] += w2 * od[a];
        }
#pragma unroll
        for (int p = 0; p < 15; ++p) {
            accr[0][p] += w0 * opr[p];  acci[0][p] += w0 * opi[p];
            accr[1][p] += w1 * opr[p];  acci[1][p] += w1 * opi[p];
            accr[2][p] += w2 * opr[p];  acci[2][p] += w2 * opi[p];
        }
    }

    // LDS reduction over 64 lanes: flat value index v = j*36 + e
    // e: 0..5 diag, 6..20 offdiag re(p=e-6), 21..35 offdiag im(p=e-21)
    __shared__ float red[108 * 65];
#pragma unroll
    for (int j = 0; j < 3; ++j) {
#pragma unroll
        for (int a = 0; a < 6; ++a) red[(j * 36 + a) * 65 + lane] = accd[j][a];
#pragma unroll
        for (int p = 0; p < 15; ++p) {
            red[(j * 36 + 6 + p) * 65 + lane]  = accr[j][p];
            red[(j * 36 + 21 + p) * 65 + lane] = acci[j][p];
        }
    }
    __syncthreads();
    for (int v = lane; v < 108; v += 64) {
        float sum = 0.0f;
        for (int i = 0; i < 64; ++i) sum += red[v * 65 + i];
        int j = v / 36, e = v % 36;
        int k = 3 * kg + j;
        float* Vf = V + (size_t)((f * K_DIM + k) * 36) * 2;
        float val = sum * (1.0f / (float)T_DIM);
        if (e < 6) {
            Vf[(e * 6 + e) * 2]     = val + 1e-6f;
            Vf[(e * 6 + e) * 2 + 1] = 0.0f;
        } else if (e < 21) {
            int p = e - 6;
            int a = (p < 1) ? 1 : (p < 3) ? 2 : (p < 6) ? 3 : (p < 10) ? 4 : 5;
            int b = p - a * (a - 1) / 2;
            Vf[(a * 6 + b) * 2] = val;
            Vf[(b * 6 + a) * 2] = val;
        } else {
            int p = e - 21;
            int a = (p < 1) ? 1 : (p < 3) ? 2 : (p < 6) ? 3 : (p < 10) ? 4 : 5;
            int b = p - a * (a - 1) / 2;
            Vf[(a * 6 + b) * 2 + 1] =  val;
            Vf[(b * 6 + a) * 2 + 1] = -val;
        }
    }
}

// ----------------------------- pass C: ISS k-loop update of W, + diff partials
__global__ __launch_bounds__(128) void passC(float* __restrict__ ws) {
    if (*(const int*)(ws + OFF_DONE)) return;
    float* Wg = ws + OFF_W;
    const float* V = ws + OFF_V;
    int tid = threadIdx.x;
    int fl = tid >> 3, m = tid & 7;      // 16 freqs/block, 8 lanes (6 active)
    int f = blockIdx.x * 16 + fl;
    bool active = (f < F_DIM) && (m < 6);

    __shared__ float Wl[16][6][6][2];
    float v[36][2];
    float w[6][2], wold[6][2];

    if (active) {
        const float* Vp = V + (size_t)((f * K_DIM + m) * 36) * 2;
#pragma unroll
        for (int i = 0; i < 36; ++i) { v[i][0] = Vp[2 * i]; v[i][1] = Vp[2 * i + 1]; }
        const float* Wp = Wg + (f * 36 + m * 6) * 2;
#pragma unroll
        for (int a = 0; a < 6; ++a) {
            w[a][0] = Wp[2 * a]; w[a][1] = Wp[2 * a + 1];
            wold[a][0] = w[a][0]; wold[a][1] = w[a][1];
            Wl[fl][m][a][0] = w[a][0]; Wl[fl][m][a][1] = w[a][1];
        }
    }
    __syncthreads();

    for (int k = 0; k < 6; ++k) {
        float wk[6][2];
        if (active) {
#pragma unroll
            for (int a = 0; a < 6; ++a) {
                wk[a][0] = Wl[fl][k][a][0];
                wk[a][1] = Wl[fl][k][a][1];
            }
        }
        __syncthreads();  // everyone read row k before anyone rewrites it
        if (active) {
            float t[6][2];
#pragma unroll
            for (int a = 0; a < 6; ++a) {
                float tr = 0.0f, ti = 0.0f;
#pragma unroll
                for (int b = 0; b < 6; ++b) {
                    float vr = v[a * 6 + b][0], vi = v[a * 6 + b][1];
                    tr += vr * wk[b][0] + vi * wk[b][1];
                    ti += vi * wk[b][0] - vr * wk[b][1];
                }
                t[a][0] = tr; t[a][1] = ti;
            }
            float quad_r = 0.0f, num_r = 0.0f, num_i = 0.0f;
#pragma unroll
            for (int a = 0; a < 6; ++a) {
                quad_r += wk[a][0] * t[a][0] - wk[a][1] * t[a][1];
                num_r  += w[a][0] * t[a][0] - w[a][1] * t[a][1];
                num_i  += w[a][0] * t[a][1] + w[a][1] * t[a][0];
            }
            float denom = fmaxf(quad_r, 1e-10f);
            float vkr, vki;
            if (m == k) {
                vkr = 1.0f - 1.0f / sqrtf(denom);
                vki = 0.0f;
            } else {
                float inv = 1.0f / denom;
                vkr = num_r * inv;
                vki = num_i * inv;
            }
#pragma unroll
            for (int a = 0; a < 6; ++a) {
                w[a][0] -= vkr * wk[a][0] - vki * wk[a][1];
                w[a][1] -= vkr * wk[a][1] + vki * wk[a][0];
            }
#pragma unroll
            for (int a = 0; a < 6; ++a) {
                Wl[fl][m][a][0] = w[a][0];
                Wl[fl][m][a][1] = w[a][1];
            }
        }
        __syncthreads();
    }

    // write back + convergence partials
    float d2 = 0.0f, o2 = 0.0f;
    if (active) {
        float* Wp = Wg + (f * 36 + m * 6) * 2;
#pragma unroll
        for (int a = 0; a < 6; ++a) {
            Wp[2 * a] = w[a][0]; Wp[2 * a + 1] = w[a][1];
            float dr = w[a][0] - wold[a][0], di = w[a][1] - wold[a][1];
            d2 += dr * dr + di * di;
            o2 += wold[a][0] * wold[a][0] + wold[a][1] * wold[a][1];
        }
    }
#pragma unroll
    for (int d = 1; d < 64; d <<= 1) {
        d2 += __shfl_xor(d2, d);
        o2 += __shfl_xor(o2, d);
    }
    __shared__ float rb[4];
    if ((tid & 63) == 0) { rb[(tid >> 6) * 2] = d2; rb[(tid >> 6) * 2 + 1] = o2; }
    __syncthreads();
    if (tid == 0) {
        ws[OFF_PART + 2 * blockIdx.x]     = rb[0] + rb[2];
        ws[OFF_PART + 2 * blockIdx.x + 1] = rb[1] + rb[3];
    }
}

// ----------------------------- convergence latch
__global__ void convk(float* __restrict__ ws) {
    if (threadIdx.x != 0) return;
    int* done = (int*)(ws + OFF_DONE);
    if (*done) return;
    float d2 = 0.0f, o2 = 0.0f;
    for (int b = 0; b < 33; ++b) {
        d2 += ws[OFF_PART + 2 * b];
        o2 += ws[OFF_PART + 2 * b + 1];
    }
    float rel = sqrtf(d2) / fmaxf(sqrtf(o2), 1.1920929e-07f);
    if (rel < 1e-5f) *done = 1;
}

// ----------------------------- final: out[k,t,f] = sum_m W[f,k,m] X[m,t,f]
__global__ __launch_bounds__(512) void finalY(const float2* __restrict__ X,
                                              const float* __restrict__ ws,
                                              float2* __restrict__ out) {
    const float2* W = (const float2*)(ws + OFF_W);
    int t = blockIdx.x;
    for (int f = threadIdx.x; f < F_DIM; f += 512) {
        float2 w[36];
#pragma unroll
        for (int i = 0; i < 36; ++i) w[i] = W[f * 36 + i];
        float2 x[6];
#pragma unroll
        for (int m = 0; m < 6; ++m) x[m] = X[(m * T_DIM + t) * F_DIM + f];
#pragma unroll
        for (int k = 0; k < 6; ++k) {
            float yr = 0.0f, yi = 0.0f;
#pragma unroll
            for (int m = 0; m < 6; ++m) {
                float2 wk = w[k * 6 + m];
                yr += wk.x * x[m].x - wk.y * x[m].y;
                yi += wk.x * x[m].y + wk.y * x[m].x;
            }
            out[(k * T_DIM + t) * F_DIM + f] = make_float2(yr, yi);
        }
    }
}

extern "C" void kernel_launch(void* const* d_in, const int* in_sizes, int n_in,
                              void* d_out, int out_size, void* d_ws, size_t ws_size,
                              hipStream_t stream) {
    const float2* X = (const float2*)d_in[0];
    float* ws = (float*)d_ws;
    float2* out = (float2*)d_out;
    float2* Xt = out;  // transposed X lives in d_out until finalY overwrites it

    initW<<<73, 256, 0, stream>>>(ws);
    transp<<<dim3(64, 17, 6), 256, 0, stream>>>(X, Xt);

    for (int it = 0; it < N_ITER; ++it) {
        passA<<<T_DIM / 8, 512, 0, stream>>>(X, ws);
        passB<<<dim3(F_DIM, 2), 64, 0, stream>>>(Xt, ws);
        passC<<<33, 128, 0, stream>>>(ws);
        convk<<<1, 64, 0, stream>>>(ws);
    }
    finalY<<<T_DIM, 512, 0, stream>>>(X, ws, out);
}